// Round 11
// baseline (123.822 us; speedup 1.0000x reference)
//
#include <hip/hip_runtime.h>

// Problem constants
#define B_DIM   4096
#define C_DIM   128
#define TOPK    8
#define K_INST  16
#define P_IDS   256          // B/K_INST
#define N_DIM   32768        // B*TOPK
#define INV_TEMP 20.0f       // 1/0.05
#define EPS 1e-6f
#define TSZ 8192             // u16 per 16 KB A-tile LDS buffer (64 rows x 128 k)

typedef unsigned short u16;
typedef __attribute__((ext_vector_type(8))) short bf16x8;
typedef __attribute__((ext_vector_type(4))) float f32x4;

struct alignas(8) U16x4 { u16 x, y, z, w; };

__device__ __forceinline__ u16 f2bf(float x) {
    union { float f; unsigned u; } v; v.f = x;
    unsigned r = v.u + 0x7fffu + ((v.u >> 16) & 1u);   // RTN-even
    return (u16)(r >> 16);
}

__device__ __forceinline__ void gload_lds16(const u16* g, u16* l) {
    __builtin_amdgcn_global_load_lds(
        (__attribute__((address_space(1))) void*)g,
        (__attribute__((address_space(3))) void*)l,
        16, 0, 0);
}

// ---------------- kernel 1: fp32 -> bf16 convert (A and S) ----------------
#define NA4 131072           // 4096*128/4
#define NTOT4 1179648        // (4096*128 + 32768*128)/4
__global__ __launch_bounds__(256) void convert_bf16(const float4* __restrict__ fa,
                                                    const float4* __restrict__ fs,
                                                    u16* __restrict__ outA,
                                                    u16* __restrict__ outS) {
    int i = blockIdx.x * 256 + threadIdx.x;
    float4 v;
    u16* dst;
    if (i < NA4) { v = fa[i]; dst = outA + (size_t)i * 4; }
    else         { int j = i - NA4; v = fs[j]; dst = outS + (size_t)j * 4; }
    U16x4 o = { f2bf(v.x), f2bf(v.y), f2bf(v.z), f2bf(v.w) };
    *(U16x4*)dst = o;
}

// ---------------- kernel 2: pipelined sim + per-block max/min ----------------
// R10 post-mortem: LDS-read pipe was the limiter (wn-waves re-read the same A
// fragments: 4 MB/CU ≈ 20 µs > MFMA 16.6 µs). R11 = ZERO-REDUNDANCY geometry:
// waves split along m only (wave = 16 rows, wm 0..3); n-split moved to the
// grid (pc = 64-col half-identity, 512 of them). Every LDS byte read exactly
// once -> 2 MB/CU ≈ 10 µs < MFMA floor. Tile 64 rows x 64 cols, 16 iters.
// LDS dbuf 32 KB -> 4 blocks/CU; ~116 VGPR -> 4 waves/SIMD.
// B pre-converted to bf16 by kernel-1 (R9 lesson: in-prologue fp32 convert
// doesn't amortize at small tiles; now prologue = 16 pure loads).
// Same swapped-operand MFMA (D = S^T: col=lane&15 indexes A-row -> register
// fold + 2 shuffles, coalesced exclusive 64B-line stores), same XOR swizzle
// via global source address, same partial vmcnt drain before each barrier.
__global__ __launch_bounds__(256, 4) void phase1(const u16* __restrict__ A,    // bf16 [4096][128]
                                                 const u16* __restrict__ Bm,   // bf16 [32768][128]
                                                 float* __restrict__ pmax,     // [512][4096]
                                                 float* __restrict__ pmin)     // [2][4096]
{
    __shared__ u16 Als[2 * TSZ];      // 32 KB double buffer

    const int tid  = threadIdx.x;     // 0..255
    const int lane = tid & 63;
    const int wm   = tid >> 6;        // wave = 16-row group (0..3)
    const int pc   = blockIdx.x;      // 64-col group 0..511 (identity p = pc>>1)
    const int h    = blockIdx.y;      // row quarter: rows h*1024..+1023
    const int r    = lane & 15;
    const int g    = lane >> 4;

    // staging: thread stages slots s = j*256+tid (j=0..3); slot s holds global
    // chunk (row = s>>4, kc = (s&15)^((s>>4)&7)); kc j-invariant (16 ≡ 0 mod 8).
    const int skc = (tid & 15) ^ ((tid >> 4) & 7);
    const u16* sbase = A + ((size_t)h * 1024 + (tid >> 4)) * C_DIM + skc * 8;

    // ---- prologue: DMA tile 0 -> buf0 (async) ----
    {
        u16* dst = &Als[tid * 8];
#pragma unroll
        for (int j = 0; j < 4; ++j)
            gload_lds16(sbase + (size_t)j * 16 * C_DIM, dst + j * 2048);
    }

    // ---- B fragments: 16 pure bf16 loads (no VALU), 64 VGPRs ----
    bf16x8 b[4][4];                   // [ni][kk]
#pragma unroll
    for (int ni = 0; ni < 4; ++ni)
#pragma unroll
        for (int kk = 0; kk < 4; ++kk)
            b[ni][kk] = *(const bf16x8*)(Bm + (size_t)(pc * 64 + ni * 16 + r) * C_DIM + kk * 32 + g * 8);

    const int  p        = pc >> 1;
    const bool diag_blk = (h == (p >> 6));
    const int  itd      = (p & 63) >> 2;      // iter holding the anchor rows
    const int  wmsel    = p & 3;              // wave holding them (16-row granularity)
    float* const pmax_w = pmax + (size_t)pc * B_DIM;

    __builtin_amdgcn_s_waitcnt(0);            // prologue DMA + B loads done
    __builtin_amdgcn_s_barrier();

    int lofs = 0;
#pragma unroll 1
    for (int it = 0; it < 16; ++it) {
        // prefetch tile it+1 into the other buffer (overlaps this iter's compute)
        if (it < 15) {
            u16* dst = &Als[(lofs ^ TSZ) + tid * 8];
            const u16* src = sbase + (size_t)(it + 1) * 64 * C_DIM;
#pragma unroll
            for (int j = 0; j < 4; ++j)
                gload_lds16(src + (size_t)j * 16 * C_DIM, dst + j * 2048);
        }

        const int row0 = h * 1024 + it * 64;

        // ---- A fragments: 4 ds_read_b128, zero cross-wave redundancy ----
        bf16x8 a[4];                  // [kk]
#pragma unroll
        for (int kk = 0; kk < 4; ++kk) {
            const int row  = wm * 16 + r;
            const int slot = row * 16 + ((kk * 4 + g) ^ (row & 7));
            a[kk] = *(const bf16x8*)&Als[lofs + slot * 8];
        }

        // ---- 16 MFMAs, swapped operands: D[n][m] (S^T tile) ----
        f32x4 acc[4] = {};            // [ni]
#pragma unroll
        for (int kk = 0; kk < 4; ++kk)
#pragma unroll
            for (int ni = 0; ni < 4; ++ni)
                acc[ni] = __builtin_amdgcn_mfma_f32_16x16x32_bf16(b[ni][kk], a[kk], acc[ni], 0, 0, 0);

        // ---- epilogue: per-A-row max over this block's 64 cols ----
        // Column m = r holds 16 n-values (ni x rr) per quad -> 15 fmax + 2 shfl;
        // lanes 0-15 store one exclusive full 64B line (R5 lesson).
        {
            float m = acc[0][0];
#pragma unroll
            for (int ni = 0; ni < 4; ++ni)
#pragma unroll
                for (int rr = 0; rr < 4; ++rr)
                    if (ni || rr) m = fmaxf(m, acc[ni][rr]);
            m = fmaxf(m, __shfl_xor(m, 16, 64));
            m = fmaxf(m, __shfl_xor(m, 32, 64));
            if (lane < 16)
                pmax_w[row0 + wm * 16 + lane] = m;
        }

        // ---- diagonal min (anchor identity's own rows) ----
        if (diag_blk && it == itd && wm == wmsel) {
            float m = fminf(acc[0][0], acc[0][1]);
#pragma unroll
            for (int ni = 0; ni < 4; ++ni)
#pragma unroll
                for (int rr = 0; rr < 4; ++rr)
                    if (ni || rr > 1) m = fminf(m, acc[ni][rr]);
            m = fminf(m, __shfl_xor(m, 16, 64));
            m = fminf(m, __shfl_xor(m, 32, 64));
            if (lane < 16)
                pmin[(size_t)(pc & 1) * B_DIM + p * 16 + lane] = m;
        }

        if (it < 15) {
            // drain the 4 prefetch DMAs; newest epilogue store stays in flight.
            // vmcnt=1, expcnt=7, lgkmcnt=15 -> 0xF71.
            __builtin_amdgcn_s_waitcnt(0xF71);
            __builtin_amdgcn_s_barrier();
        }
        lofs ^= TSZ;
    }
}

// ---------------- kernel 3: per-row loss + mean ----------------
// grid 256 blocks x 256 threads; block = 16 rows. Lanes r=0..15 read 64B-line
// chunks of [pc][row]; 16 p-groups partial-sum via LDS. Folds 2 pc-halves.
__global__ __launch_bounds__(256) void phase2(const float* __restrict__ pmax,  // [512][4096]
                                              const float* __restrict__ pmin,  // [2][4096]
                                              const int* __restrict__ labels,
                                              float* __restrict__ out) {
    const int tid = threadIdx.x;
    const int r   = tid & 15;
    const int pg  = tid >> 4;
    const int row = blockIdx.x * 16 + r;
    const int pid = labels[row];
    const float* base = pmax + row;
    float s = 0.f;
#pragma unroll
    for (int j = 0; j < 16; ++j) {
        const int p = pg * 16 + j;
        const float v = fmaxf(base[(size_t)(2 * p) * B_DIM],
                              base[(size_t)(2 * p + 1) * B_DIM]);
        s += (p == pid) ? 0.f : __expf(v * INV_TEMP);
    }
    __shared__ float part[16][17];
    part[pg][r] = s;
    __syncthreads();
    if (tid < 16) {
        float neg = 0.f;
#pragma unroll
        for (int j = 0; j < 16; ++j) neg += part[j][tid];
        const int rw = blockIdx.x * 16 + tid;
        const float mn  = fminf(pmin[rw], pmin[B_DIM + rw]);
        const float pos = __expf(mn * INV_TEMP);
        float loss = -__logf(pos / (pos + neg + EPS) + EPS);
        loss += __shfl_xor(loss, 1, 64);
        loss += __shfl_xor(loss, 2, 64);
        loss += __shfl_xor(loss, 4, 64);
        loss += __shfl_xor(loss, 8, 64);
        if (tid == 0) atomicAdd(out, loss * (1.0f / (float)B_DIM));
    }
}

extern "C" void kernel_launch(void* const* d_in, const int* in_sizes, int n_in,
                              void* d_out, int out_size, void* d_ws, size_t ws_size,
                              hipStream_t stream) {
    const float* feats   = (const float*)d_in[0];   // [4096,128]
    const float* feats_s = (const float*)d_in[1];   // [4096,8,128]
    const int*   labels  = (const int*)d_in[2];     // [4096]
    float* out = (float*)d_out;

    // workspace: bf16 A (1 MB) | bf16 S (8 MB) | pmax (8 MB) | pmin (32 KB)
    u16* wsA = (u16*)d_ws;
    u16* wsS = wsA + (size_t)B_DIM * C_DIM;
    float* pmax = (float*)((char*)d_ws + (9u << 20));
    float* pmin = pmax + (size_t)512 * B_DIM;

    hipMemsetAsync(d_out, 0, sizeof(float), stream);
    convert_bf16<<<NTOT4 / 256, 256, 0, stream>>>((const float4*)feats, (const float4*)feats_s, wsA, wsS);
    dim3 g1(512, 4);
    phase1<<<g1, 256, 0, stream>>>(wsA, wsS, pmax, pmin);
    phase2<<<B_DIM / 16, 256, 0, stream>>>(pmax, pmin, labels, out);
}

// Round 12
// 118.659 us; speedup vs baseline: 1.0435x; 1.0435x over previous
//
#include <hip/hip_runtime.h>

// Problem constants
#define B_DIM   4096
#define C_DIM   128
#define TOPK    8
#define K_INST  16
#define P_IDS   256          // B/K_INST
#define N_DIM   32768        // B*TOPK
#define INV_TEMP 20.0f       // 1/0.05
#define EPS 1e-6f
#define TSZ 16384            // u16 per 32 KB A-tile LDS buffer (128 rows x 128 k)

typedef unsigned short u16;
typedef __attribute__((ext_vector_type(8))) short bf16x8;
typedef __attribute__((ext_vector_type(16))) float f32x16;

struct alignas(8) U16x4 { u16 x, y, z, w; };

__device__ __forceinline__ u16 f2bf(float x) {
    union { float f; unsigned u; } v; v.f = x;
    unsigned r = v.u + 0x7fffu + ((v.u >> 16) & 1u);   // RTN-even
    return (u16)(r >> 16);
}

__device__ __forceinline__ void gload_lds16(const u16* g, u16* l) {
    __builtin_amdgcn_global_load_lds(
        (__attribute__((address_space(1))) void*)g,
        (__attribute__((address_space(3))) void*)l,
        16, 0, 0);
}

// ---------------- kernel 1: fp32 -> bf16 convert (A and S) + out zero ----------------
// Also zeroes the output scalar, replacing the hipMemsetAsync dispatch
// (R11 post-mortem: ~18 us of launch overhead per dispatch; 4 -> 3 dispatches).
#define NA4 131072           // 4096*128/4
#define NTOT4 1179648        // (4096*128 + 32768*128)/4
__global__ __launch_bounds__(256) void convert_bf16(const float4* __restrict__ fa,
                                                    const float4* __restrict__ fs,
                                                    u16* __restrict__ outA,
                                                    u16* __restrict__ outS,
                                                    float* __restrict__ out) {
    int i = blockIdx.x * 256 + threadIdx.x;
    if (i == 0) *out = 0.f;
    float4 v;
    u16* dst;
    if (i < NA4) { v = fa[i]; dst = outA + (size_t)i * 4; }
    else         { int j = i - NA4; v = fs[j]; dst = outS + (size_t)j * 4; }
    U16x4 o = { f2bf(v.x), f2bf(v.y), f2bf(v.z), f2bf(v.w) };
    *(U16x4*)dst = o;
}

// ---------------- kernel 2: pipelined sim + per-block max/min ----------------
// R8-R11 post-mortem: four different geometries all pin at 46-49 us (~750 TF,
// the m97-class plateau); no pipe >30% busy. R12 keeps the proven structure
// (zero-redundancy m-split waves, XOR-swizzled DMA staging, partial drains)
// but moves to mfma_f32_32x32x16_bf16: 17% better rate (2495 vs 2075 TF
// ubench) and ~half the MFMA/epilogue instruction count.
// grid (512 pc, 2 h), block 256 thr (4 waves, wm = wave = 32-row group),
// tile 128 rows x 64 cols, 16 iters. LDS dbuf 2x32 KB.
// Swapped operands: D = B-op x A-op, so D's col (lane&31) indexes the A-row:
// row-max = fold 32 regs + ONE shfl_xor(32); lanes 0..31 store 128 B of
// consecutive rows (exclusive lines - R5 lesson). Operand layout (m74/m101
// family): [idx = lane&31][k = (lane>>5)*8 + j]; C/D row n = (reg&3) +
// 8*(reg>>2) + 4*(lane>>5).
__global__ __launch_bounds__(256, 2) void phase1(const u16* __restrict__ A,    // bf16 [4096][128]
                                                 const u16* __restrict__ Bm,   // bf16 [32768][128]
                                                 float* __restrict__ pmax,     // [512][4096]
                                                 float* __restrict__ pmin)     // [2][4096]
{
    __shared__ u16 Als[2 * TSZ];      // 64 KB double buffer

    const int tid  = threadIdx.x;     // 0..255
    const int lane = tid & 63;
    const int wm   = tid >> 6;        // wave = 32-row group (0..3)
    const int pc   = blockIdx.x;      // 64-col group 0..511 (identity p = pc>>1)
    const int h    = blockIdx.y;      // row half: rows h*2048..+2047
    const int m5   = lane & 31;       // operand idx within 32
    const int t    = lane >> 5;       // k-half (0/1)

    // staging: thread stages slots s = j*256+tid (j=0..7); slot s holds global
    // chunk (row = s>>4, kc = (s&15)^((s>>4)&7)); kc j-invariant (16 = 0 mod 8).
    const int skc = (tid & 15) ^ ((tid >> 4) & 7);
    const u16* sbase = A + ((size_t)h * 2048 + (tid >> 4)) * C_DIM + skc * 8;

    // ---- prologue: DMA tile 0 -> buf0 (async) ----
    {
        u16* dst = &Als[tid * 8];
#pragma unroll
        for (int j = 0; j < 8; ++j)
            gload_lds16(sbase + (size_t)j * 16 * C_DIM, dst + j * 2048);
    }

    // ---- B fragments: 16 pure bf16 loads (no VALU), 64 VGPRs ----
    // b[nc][kk]: B-col n = pc*64 + nc*32 + m5, k = kk*16 + t*8 + j
    bf16x8 b[2][8];
#pragma unroll
    for (int nc = 0; nc < 2; ++nc)
#pragma unroll
        for (int kk = 0; kk < 8; ++kk)
            b[nc][kk] = *(const bf16x8*)(Bm + (size_t)(pc * 64 + nc * 32 + m5) * C_DIM + kk * 16 + t * 8);

    const int  p        = pc >> 1;
    const bool diag_blk = (h == (p >> 7));
    const int  itd      = (p & 127) >> 3;     // iter holding the anchor rows
    const int  wmsel    = (p & 7) >> 1;       // wave holding them
    const int  hsel     = p & 1;              // 16-row half within the wave's 32
    float* const pmax_w = pmax + (size_t)pc * B_DIM;

    __builtin_amdgcn_s_waitcnt(0);            // prologue DMA + B loads done
    __builtin_amdgcn_s_barrier();

    int lofs = 0;
#pragma unroll 1
    for (int it = 0; it < 16; ++it) {
        // prefetch tile it+1 into the other buffer (overlaps this iter's compute)
        if (it < 15) {
            u16* dst = &Als[(lofs ^ TSZ) + tid * 8];
            const u16* src = sbase + (size_t)(it + 1) * 128 * C_DIM;
#pragma unroll
            for (int j = 0; j < 8; ++j)
                gload_lds16(src + (size_t)j * 16 * C_DIM, dst + j * 2048);
        }

        const int row0 = h * 2048 + it * 128;

        // ---- A fragments: 8 ds_read_b128, zero cross-wave redundancy ----
        // a[kk]: A-row m = wm*32 + m5, k = kk*16 + t*8 + j -> chunk kc = kk*2+t
        bf16x8 a[8];
        {
            const int row = wm * 32 + m5;
#pragma unroll
            for (int kk = 0; kk < 8; ++kk) {
                const int slot = row * 16 + ((kk * 2 + t) ^ (row & 7));
                a[kk] = *(const bf16x8*)&Als[lofs + slot * 8];
            }
        }

        // ---- 16 MFMAs (32x32x16), swapped operands: D[n][m] ----
        f32x16 acc[2] = {};           // [nc]
#pragma unroll
        for (int kk = 0; kk < 8; ++kk)
#pragma unroll
            for (int nc = 0; nc < 2; ++nc)
                acc[nc] = __builtin_amdgcn_mfma_f32_32x32x16_bf16(b[nc][kk], a[kk], acc[nc], 0, 0, 0);

        // ---- epilogue: per-A-row max over this block's 64 cols ----
        // Lane holds col m = m5: 32 n-values (2 nc x 16 regs) -> 31 fmax +
        // shfl_xor(32) (lane-halves carry complementary n subsets); lanes
        // 0..31 store 128 B of consecutive rows (2 exclusive 64B lines).
        {
            float m = acc[0][0];
#pragma unroll
            for (int nc = 0; nc < 2; ++nc)
#pragma unroll
                for (int rr = 0; rr < 16; ++rr)
                    if (nc || rr) m = fmaxf(m, acc[nc][rr]);
            m = fmaxf(m, __shfl_xor(m, 32, 64));
            if (lane < 32)
                pmax_w[row0 + wm * 32 + lane] = m;
        }

        // ---- diagonal min (anchor identity's own 16 rows) ----
        if (diag_blk && it == itd && wm == wmsel) {
            float m = fminf(acc[0][0], acc[0][1]);
#pragma unroll
            for (int nc = 0; nc < 2; ++nc)
#pragma unroll
                for (int rr = 0; rr < 16; ++rr)
                    if (nc || rr > 1) m = fminf(m, acc[nc][rr]);
            m = fminf(m, __shfl_xor(m, 32, 64));
            // anchor rows are the hsel half of this wave's 32: lanes
            // hsel*16..hsel*16+15 store 16 consecutive floats (one 64B line).
            if (lane < 32 && (lane >> 4) == hsel)
                pmin[(size_t)(pc & 1) * B_DIM + p * 16 + (lane & 15)] = m;
        }

        if (it < 15) {
            // drain the 8 prefetch DMAs; newest epilogue store stays in
            // flight. vmcnt=1, expcnt=7, lgkmcnt=15 -> 0xF71.
            __builtin_amdgcn_s_waitcnt(0xF71);
            __builtin_amdgcn_s_barrier();
        }
        lofs ^= TSZ;
    }
}

// ---------------- kernel 3: per-row loss + mean ----------------
// grid 256 blocks x 256 threads; block = 16 rows. Lanes r=0..15 read 64B-line
// chunks of [pc][row]; 16 p-groups partial-sum via LDS. Folds 2 pc-halves.
__global__ __launch_bounds__(256) void phase2(const float* __restrict__ pmax,  // [512][4096]
                                              const float* __restrict__ pmin,  // [2][4096]
                                              const int* __restrict__ labels,
                                              float* __restrict__ out) {
    const int tid = threadIdx.x;
    const int r   = tid & 15;
    const int pg  = tid >> 4;
    const int row = blockIdx.x * 16 + r;
    const int pid = labels[row];
    const float* base = pmax + row;
    float s = 0.f;
#pragma unroll
    for (int j = 0; j < 16; ++j) {
        const int p = pg * 16 + j;
        const float v = fmaxf(base[(size_t)(2 * p) * B_DIM],
                              base[(size_t)(2 * p + 1) * B_DIM]);
        s += (p == pid) ? 0.f : __expf(v * INV_TEMP);
    }
    __shared__ float part[16][17];
    part[pg][r] = s;
    __syncthreads();
    if (tid < 16) {
        float neg = 0.f;
#pragma unroll
        for (int j = 0; j < 16; ++j) neg += part[j][tid];
        const int rw = blockIdx.x * 16 + tid;
        const float mn  = fminf(pmin[rw], pmin[B_DIM + rw]);
        const float pos = __expf(mn * INV_TEMP);
        float loss = -__logf(pos / (pos + neg + EPS) + EPS);
        loss += __shfl_xor(loss, 1, 64);
        loss += __shfl_xor(loss, 2, 64);
        loss += __shfl_xor(loss, 4, 64);
        loss += __shfl_xor(loss, 8, 64);
        if (tid == 0) atomicAdd(out, loss * (1.0f / (float)B_DIM));
    }
}

extern "C" void kernel_launch(void* const* d_in, const int* in_sizes, int n_in,
                              void* d_out, int out_size, void* d_ws, size_t ws_size,
                              hipStream_t stream) {
    const float* feats   = (const float*)d_in[0];   // [4096,128]
    const float* feats_s = (const float*)d_in[1];   // [4096,8,128]
    const int*   labels  = (const int*)d_in[2];     // [4096]
    float* out = (float*)d_out;

    // workspace: bf16 A (1 MB) | bf16 S (8 MB) | pmax (8 MB) | pmin (32 KB)
    u16* wsA = (u16*)d_ws;
    u16* wsS = wsA + (size_t)B_DIM * C_DIM;
    float* pmax = (float*)((char*)d_ws + (9u << 20));
    float* pmin = pmax + (size_t)512 * B_DIM;

    convert_bf16<<<NTOT4 / 256, 256, 0, stream>>>((const float4*)feats, (const float4*)feats_s, wsA, wsS, out);
    dim3 g1(512, 2);
    phase1<<<g1, 256, 0, stream>>>(wsA, wsS, pmax, pmin);
    phase2<<<B_DIM / 16, 256, 0, stream>>>(pmax, pmin, labels, out);
}